// Round 1
// baseline (530.394 us; speedup 1.0000x reference)
//
#include <hip/hip_runtime.h>

#define NN 64
#define CCH 256          // channels
#define KK 196           // k spatial (14x14)
#define KPAD 256         // padded columns
#define CB 32            // c-chunk staged in LDS
#define ROWS 32          // pq rows per workgroup
#define NSLOTS (14 * NN) // 896 (term, n) slots

__device__ __forceinline__ float waveMin(float v) {
#pragma unroll
  for (int m = 1; m < 64; m <<= 1) v = fminf(v, __shfl_xor(v, m, 64));
  return v;
}

__device__ __forceinline__ float waveSum(float v) {
#pragma unroll
  for (int m = 1; m < 64; m <<= 1) v += __shfl_xor(v, m, 64);
  return v;
}

__global__ void __launch_bounds__(256) zero_ws_kernel(float* ws) {
  int i = blockIdx.x * 256 + threadIdx.x;
  if (i < 3 * NSLOTS) ws[i] = 0.0f;
}

__global__ void __launch_bounds__(256, 2) triplet_main(
    const float* __restrict__ gl_sa, const float* __restrict__ lo_sa,
    const float* __restrict__ gl_pr, const float* __restrict__ coords,
    float* __restrict__ ws) {
  __shared__ float kbuf[CB][KPAD]; // 32 KB
  __shared__ float qbuf[CB][ROWS]; // 4 KB

  const int tid = threadIdx.x;
  const int lane = tid & 63;
  const int w = tid >> 6;
  const int r0 = w * 8;

  int b = blockIdx.x;
  const float *qptr, *kptr, *cqp, *ckp;
  int Q, Wq, slot, pq0;
  if (b < 2 * NN * 7) {
    // gl terms: t=0 -> q=gl_sa[1],k=gl_pr[0]; t=1 -> q=gl_sa[0],k=gl_pr[1]
    int t = b / (NN * 7);
    int rem = b % (NN * 7);
    int n = rem / 7;
    pq0 = (rem % 7) * ROWS;
    int qi = 1 - t, kj = t;
    Q = 196; Wq = 14;
    qptr = gl_sa + (size_t)(qi * NN + n) * CCH * 196;
    kptr = gl_pr + (size_t)(kj * NN + n) * CCH * 196;
    cqp = coords + (qi * NN + n) * 4;
    ckp = coords + (kj * NN + n) * 4;
    slot = t * NN + n;
  } else {
    // lo terms: t = j*6 + i
    int bb = b - 2 * NN * 7;
    int t = bb / (NN * 4);
    int rem = bb % (NN * 4);
    int n = rem / 4;
    pq0 = (rem % 4) * ROWS;
    int j = t / 6, i = t % 6;
    Q = 100; Wq = 10;
    qptr = lo_sa + (size_t)(i * NN + n) * CCH * 100;
    kptr = gl_pr + (size_t)(j * NN + n) * CCH * 196;
    cqp = coords + ((2 + i) * NN + n) * 4;
    ckp = coords + (j * NN + n) * 4;
    slot = (2 + t) * NN + n;
  }

  float4 acc[8];
#pragma unroll
  for (int i = 0; i < 8; ++i) acc[i] = make_float4(0.f, 0.f, 0.f, 0.f);

  for (int c0 = 0; c0 < CCH; c0 += CB) {
    // stage K chunk: kbuf[cc][0..195] real, 196..255 zero
#pragma unroll
    for (int s = 0; s < 8; ++s) {
      int g = tid + s * 256;
      int cc = g >> 6;
      int c4 = g & 63;
      float4 v = make_float4(0.f, 0.f, 0.f, 0.f);
      if (c4 < 49) v = *(const float4*)(kptr + (size_t)(c0 + cc) * KK + 4 * c4);
      *(float4*)&kbuf[cc][4 * c4] = v;
    }
    // stage Q chunk (rows beyond Q -> 0)
#pragma unroll
    for (int s = 0; s < 4; ++s) {
      int e = tid + s * 256;
      int cc = e >> 5;
      int r = e & 31;
      int pq = pq0 + r;
      qbuf[cc][r] = (pq < Q) ? qptr[(size_t)(c0 + cc) * Q + pq] : 0.0f;
    }
    __syncthreads();
#pragma unroll
    for (int cc = 0; cc < CB; ++cc) {
      const float4 kv = *(const float4*)&kbuf[cc][lane * 4];
      const float4 qa = *(const float4*)&qbuf[cc][r0];
      const float4 qb = *(const float4*)&qbuf[cc][r0 + 4];
      acc[0].x += qa.x * kv.x; acc[0].y += qa.x * kv.y; acc[0].z += qa.x * kv.z; acc[0].w += qa.x * kv.w;
      acc[1].x += qa.y * kv.x; acc[1].y += qa.y * kv.y; acc[1].z += qa.y * kv.z; acc[1].w += qa.y * kv.w;
      acc[2].x += qa.z * kv.x; acc[2].y += qa.z * kv.y; acc[2].z += qa.z * kv.z; acc[2].w += qa.z * kv.w;
      acc[3].x += qa.w * kv.x; acc[3].y += qa.w * kv.y; acc[3].z += qa.w * kv.z; acc[3].w += qa.w * kv.w;
      acc[4].x += qb.x * kv.x; acc[4].y += qb.x * kv.y; acc[4].z += qb.x * kv.z; acc[4].w += qb.x * kv.w;
      acc[5].x += qb.y * kv.x; acc[5].y += qb.y * kv.y; acc[5].z += qb.y * kv.z; acc[5].w += qb.y * kv.w;
      acc[6].x += qb.z * kv.x; acc[6].y += qb.z * kv.y; acc[6].z += qb.z * kv.z; acc[6].w += qb.z * kv.w;
      acc[7].x += qb.w * kv.x; acc[7].y += qb.w * kv.y; acc[7].z += qb.w * kv.z; acc[7].w += qb.w * kv.w;
    }
    __syncthreads();
  }

  // geometry
  const float qx0 = cqp[0], qy0 = cqp[1];
  const float bwq = (cqp[2] - qx0) / (float)Wq;
  const float bhq = (cqp[3] - qy0) / (float)Wq; // Hq == Wq
  const float kx0 = ckp[0], ky0 = ckp[1];
  const float bwk = (ckp[2] - kx0) / 14.0f;
  const float bhk = (ckp[3] - ky0) / 14.0f;
  const float qd = sqrtf(bwq * bwq + bhq * bhq);
  const float kd = sqrtf(bwk * bwk + bhk * bhk);
  const float md = fmaxf(qd, kd);
  const float INFV = __builtin_inff();

  float ckxv[4], ckyv[4];
  bool kval[4];
#pragma unroll
  for (int j = 0; j < 4; ++j) {
    int pk = lane * 4 + j;
    kval[j] = (pk < KK);
    int xk = pk % 14, yk = pk / 14;
    ckxv[j] = ((float)xk + 0.5f) * bwk + kx0;
    ckyv[j] = ((float)yk + 0.5f) * bhk + ky0;
  }

  float psum = 0.f, pcnt = 0.f, nsum = 0.f;
#pragma unroll
  for (int i = 0; i < 8; ++i) {
    int pq = pq0 + r0 + i; // wave-uniform
    if (pq < Q) {
      int x = pq % Wq, y = pq / Wq;
      float cqx = ((float)x + 0.5f) * bwq + qx0;
      float cqy = ((float)y + 0.5f) * bhq + qy0;
      float vr[4] = {acc[i].x, acc[i].y, acc[i].z, acc[i].w};
      float mv[4];
#pragma unroll
      for (int j = 0; j < 4; ++j) {
        float v = -2.0f * vr[j];
        float dx = cqx - ckxv[j];
        float dy = cqy - ckyv[j];
        float dist = sqrtf(dx * dx + dy * dy) / md;
        bool pos = kval[j] && (dist < 0.7f);
        psum += pos ? v : 0.0f;
        pcnt += pos ? 1.0f : 0.0f;
        mv[j] = (kval[j] && !pos) ? v : INFV;
      }
      // extract 10 smallest across the wave (multiset semantics: kill one
      // instance per iteration), drop the smallest, mean the other 9.
      float total = 0.f, first = 0.f;
#pragma unroll 1
      for (int tsel = 0; tsel < 10; ++tsel) {
        float lm = fminf(fminf(mv[0], mv[1]), fminf(mv[2], mv[3]));
        float m = waveMin(lm);
        if (tsel == 0) first = m;
        total += m;
        bool has = (mv[0] == m) || (mv[1] == m) || (mv[2] == m) || (mv[3] == m);
        unsigned long long bal = __ballot(has);
        int leader = __ffsll((long long)bal) - 1;
        if (lane == leader) {
          if (mv[0] == m) mv[0] = INFV;
          else if (mv[1] == m) mv[1] = INFV;
          else if (mv[2] == m) mv[2] = INFV;
          else mv[3] = INFV;
        }
      }
      nsum += (total - first) * (1.0f / 9.0f);
    }
  }

  psum = waveSum(psum);
  pcnt = waveSum(pcnt);
  if (lane == 0) {
    atomicAdd(&ws[slot], psum);
    atomicAdd(&ws[NSLOTS + slot], pcnt);
    atomicAdd(&ws[2 * NSLOTS + slot], nsum);
  }
}

__global__ void __launch_bounds__(256) finalize_kernel(const float* __restrict__ ws,
                                                       float* __restrict__ out) {
  int tid = threadIdx.x;
  float sum = 0.f;
  for (int e = tid; e < NSLOTS; e += 256) {
    float Qf = (e < 2 * NN) ? 196.0f : 100.0f;
    float positives = ws[e] / (ws[NSLOTS + e] + 1e-6f);
    float negatives = ws[2 * NSLOTS + e] / Qf;
    sum += fmaxf(0.0f, 100.0f - (negatives - 2.0f * positives));
  }
  sum = waveSum(sum);
  __shared__ float ssum[4];
  if ((tid & 63) == 0) ssum[tid >> 6] = sum;
  __syncthreads();
  if (tid == 0) out[0] = (ssum[0] + ssum[1] + ssum[2] + ssum[3]) * (1.0f / NSLOTS);
}

extern "C" void kernel_launch(void* const* d_in, const int* in_sizes, int n_in,
                              void* d_out, int out_size, void* d_ws, size_t ws_size,
                              hipStream_t stream) {
  const float* gl_sa = (const float*)d_in[0];
  const float* lo_sa = (const float*)d_in[1];
  const float* gl_pr = (const float*)d_in[2];
  const float* coords = (const float*)d_in[3];
  float* ws = (float*)d_ws;
  float* out = (float*)d_out;

  zero_ws_kernel<<<(3 * NSLOTS + 255) / 256, 256, 0, stream>>>(ws);
  triplet_main<<<2 * NN * 7 + 12 * NN * 4, 256, 0, stream>>>(gl_sa, lo_sa, gl_pr, coords, ws);
  finalize_kernel<<<1, 256, 0, stream>>>(ws, out);
}

// Round 2
// 253.158 us; speedup vs baseline: 2.0951x; 2.0951x over previous
//
#include <hip/hip_runtime.h>

#define NN 64
#define NSLOTS (14 * NN) // 896 (term, n) slots

typedef __attribute__((ext_vector_type(8))) short short8;
typedef __attribute__((ext_vector_type(4))) float f32x4;

__device__ __forceinline__ float waveSum(float v) {
#pragma unroll
  for (int m = 1; m < 64; m <<= 1) v += __shfl_xor(v, m, 64);
  return v;
}

// RNE float -> bf16 (matches v_cvt semantics for finite values)
__device__ __forceinline__ unsigned short f2bf(float f) {
  unsigned u = __builtin_bit_cast(unsigned, f);
  u += 0x7FFFu + ((u >> 16) & 1u);
  return (unsigned short)(u >> 16);
}
__device__ __forceinline__ unsigned packbf(float a, float b) {
  return (unsigned)f2bf(a) | ((unsigned)f2bf(b) << 16);
}

__global__ void __launch_bounds__(256) zero_ws_kernel(float* ws) {
  int i = blockIdx.x * 256 + threadIdx.x;
  if (i < 3 * NSLOTS) ws[i] = 0.0f;
}

__global__ void __launch_bounds__(256, 4) triplet_main(
    const float* __restrict__ gl_sa, const float* __restrict__ lo_sa,
    const float* __restrict__ gl_pr, const float* __restrict__ coords,
    float* __restrict__ ws) {
  // Fragment-order LDS: [kc][col][quad][8 bf16]  (one k-step = 32 channels)
  __shared__ short bbuf[2][224][4][8]; // 28672 B  (K matrix, cols 0..223)
  __shared__ short abuf[2][64][4][8];  //  8192 B  (Q matrix, 64-row group)

  const int tid = threadIdx.x;
  const int lane = tid & 63;
  const int li = lane & 15;   // fragment m/n index
  const int quad = lane >> 4; // fragment k-group / C-row group
  const int w = tid >> 6;     // wave id = 16-row strip within 64-row group

  int b = blockIdx.x;
  const float *qptr, *kptr, *cqp, *ckp;
  int Q, Wq, slot, rowbase;
  if (b < 512) {
    // gl terms: t=0 -> q=gl_sa[1],k=gl_pr[0]; t=1 -> q=gl_sa[0],k=gl_pr[1]
    int t = b >> 8, rem = b & 255;
    int n = rem >> 2, g = rem & 3;
    rowbase = g * 64;
    int qi = 1 - t, kj = t;
    Q = 196; Wq = 14;
    qptr = gl_sa + (size_t)(qi * NN + n) * 256 * 196;
    kptr = gl_pr + (size_t)(kj * NN + n) * 256 * 196;
    cqp = coords + (qi * NN + n) * 4;
    ckp = coords + (kj * NN + n) * 4;
    slot = t * NN + n;
  } else {
    int bb = b - 512;
    int t = bb / 128, rem = bb % 128;
    int n = rem >> 1, g = rem & 1;
    rowbase = g * 64;
    int j = t / 6, i = t % 6;
    Q = 100; Wq = 10;
    qptr = lo_sa + (size_t)(i * NN + n) * 256 * 100;
    kptr = gl_pr + (size_t)(j * NN + n) * 256 * 196;
    cqp = coords + ((2 + i) * NN + n) * 4;
    ckp = coords + (j * NN + n) * 4;
    slot = (2 + t) * NN + n;
  }

  // zero the never-staged B cols 196..223 (stay zero across all chunks)
  for (int t = tid; t < 896; t += 256) {
    int kc = t / 448, r2 = t % 448;      // 28 cols x 16 uints
    int col = 196 + (r2 >> 4), e = r2 & 15;
    ((unsigned*)&bbuf[kc][col][0][0])[e] = 0;
  }

  f32x4 acc[14];
#pragma unroll
  for (int t = 0; t < 14; ++t) acc[t] = 0.0f;

#pragma unroll 1
  for (int c0 = 0; c0 < 256; c0 += 64) {
    // ---- stage B chunk: 32 channel-pairs x 49 col-quads = 1568 tasks ----
#pragma unroll
    for (int it = 0; it < 7; ++it) {
      int t = tid + it * 256;
      if (t < 1568) {
        int cp = t / 49, cq = t % 49;
        int cc = 2 * cp;
        const float* p = kptr + (size_t)(c0 + cc) * 196 + 4 * cq;
        float4 v0 = *(const float4*)p;
        float4 v1 = *(const float4*)(p + 196);
        int kc = cc >> 5, kk = cc & 31;
        unsigned* d = (unsigned*)&bbuf[kc][4 * cq][kk >> 3][kk & 7];
        d[0]  = packbf(v0.x, v1.x);   // col stride = 16 uints
        d[16] = packbf(v0.y, v1.y);
        d[32] = packbf(v0.z, v1.z);
        d[48] = packbf(v0.w, v1.w);
      }
    }
    // ---- stage A chunk: 32 channel-pairs x 16 row-quads = 512 tasks ----
#pragma unroll
    for (int it = 0; it < 2; ++it) {
      int t = tid + it * 256;
      int cp = t >> 4, cq = t & 15;
      int cc = 2 * cp;
      int pq = rowbase + 4 * cq;
      float4 v0 = make_float4(0.f, 0.f, 0.f, 0.f), v1 = v0;
      if (pq <= Q - 4) {
        const float* p = qptr + (size_t)(c0 + cc) * Q + pq;
        v0 = *(const float4*)p;
        v1 = *(const float4*)(p + Q);
      }
      int kc = cc >> 5, kk = cc & 31;
      unsigned* d = (unsigned*)&abuf[kc][4 * cq][kk >> 3][kk & 7];
      d[0]  = packbf(v0.x, v1.x);
      d[16] = packbf(v0.y, v1.y);
      d[32] = packbf(v0.z, v1.z);
      d[48] = packbf(v0.w, v1.w);
    }
    __syncthreads();
    // ---- MFMA: 2 k-steps x 14 col-tiles ----
#pragma unroll
    for (int kc = 0; kc < 2; ++kc) {
      short8 af = *(const short8*)&abuf[kc][w * 16 + li][quad][0];
#pragma unroll
      for (int t = 0; t < 14; ++t) {
        short8 bf = *(const short8*)&bbuf[kc][t * 16 + li][quad][0];
        acc[t] = __builtin_amdgcn_mfma_f32_16x16x32_bf16(af, bf, acc[t], 0, 0, 0);
      }
    }
    __syncthreads();
  }

  // ---- geometry ----
  const float qx0 = cqp[0], qy0 = cqp[1];
  const float bwq = (cqp[2] - qx0) / (float)Wq;
  const float bhq = (cqp[3] - qy0) / (float)Wq;
  const float kx0 = ckp[0], ky0 = ckp[1];
  const float bwk = (ckp[2] - kx0) / 14.0f;
  const float bhk = (ckp[3] - ky0) / 14.0f;
  const float qd = sqrtf(bwq * bwq + bhq * bhq);
  const float kd = sqrtf(bwk * bwk + bhk * bhk);
  const float md = fmaxf(qd, kd);
  const float INFV = __builtin_inff();

  float ckx[14], cky[14];
  unsigned kvalid = 0;
#pragma unroll
  for (int t = 0; t < 14; ++t) {
    int col = t * 16 + li;
    if (col < 196) kvalid |= (1u << t);
    int xk = col % 14, yk = col / 14;
    ckx[t] = ((float)xk + 0.5f) * bwk + kx0;
    cky[t] = ((float)yk + 0.5f) * bhk + ky0;
  }

  // ---- fused epilogue on MFMA C layout: quad owns rows quad*4+reg ----
  float psum = 0.f, pcnt = 0.f, nsum = 0.f;
#pragma unroll
  for (int rg = 0; rg < 4; ++rg) {
    int r = rowbase + w * 16 + quad * 4 + rg; // quad-uniform
    if (r < Q) {
      int x = r % Wq, y = r / Wq;
      float cqx = ((float)x + 0.5f) * bwq + qx0;
      float cqy = ((float)y + 0.5f) * bhq + qy0;
      float mv[14];
#pragma unroll
      for (int t = 0; t < 14; ++t) {
        float v = -2.0f * acc[t][rg];
        float dx = cqx - ckx[t], dy = cqy - cky[t];
        float dist = sqrtf(dx * dx + dy * dy) / md;
        bool kv = (kvalid >> t) & 1;
        bool pos = kv && (dist < 0.7f);
        psum += pos ? v : 0.0f;
        pcnt += pos ? 1.0f : 0.0f;
        mv[t] = (kv && !pos) ? v : INFV;
      }
      float total = 0.f, first = 0.f;
#pragma unroll 1
      for (int s = 0; s < 10; ++s) {
        float lm = mv[0];
#pragma unroll
        for (int t = 1; t < 14; ++t) lm = fminf(lm, mv[t]);
        float m = lm;
        m = fminf(m, __shfl_xor(m, 1));
        m = fminf(m, __shfl_xor(m, 2));
        m = fminf(m, __shfl_xor(m, 4));
        m = fminf(m, __shfl_xor(m, 8));
        if (s == 0) first = m;
        total += m;
        unsigned long long bal = __ballot(lm == m);
        unsigned qb = (unsigned)((bal >> (quad * 16)) & 0xFFFFull);
        int leader = __ffs(qb) - 1;
        if (li == leader) {
          bool done = false;
#pragma unroll
          for (int t = 0; t < 14; ++t) {
            bool hit = !done && (mv[t] == m);
            mv[t] = hit ? INFV : mv[t];
            done = done || hit;
          }
        }
      }
      if (li == 0) nsum += (total - first) * (1.0f / 9.0f);
    }
  }

  psum = waveSum(psum);
  pcnt = waveSum(pcnt);
  nsum = waveSum(nsum);
  if (lane == 0) {
    atomicAdd(&ws[slot], psum);
    atomicAdd(&ws[NSLOTS + slot], pcnt);
    atomicAdd(&ws[2 * NSLOTS + slot], nsum);
  }
}

__global__ void __launch_bounds__(256) finalize_kernel(const float* __restrict__ ws,
                                                       float* __restrict__ out) {
  int tid = threadIdx.x;
  float sum = 0.f;
  for (int e = tid; e < NSLOTS; e += 256) {
    float Qf = (e < 2 * NN) ? 196.0f : 100.0f;
    float positives = ws[e] / (ws[NSLOTS + e] + 1e-6f);
    float negatives = ws[2 * NSLOTS + e] / Qf;
    sum += fmaxf(0.0f, 100.0f - (negatives - 2.0f * positives));
  }
  sum = waveSum(sum);
  __shared__ float ssum[4];
  if ((tid & 63) == 0) ssum[tid >> 6] = sum;
  __syncthreads();
  if (tid == 0) out[0] = (ssum[0] + ssum[1] + ssum[2] + ssum[3]) * (1.0f / NSLOTS);
}

extern "C" void kernel_launch(void* const* d_in, const int* in_sizes, int n_in,
                              void* d_out, int out_size, void* d_ws, size_t ws_size,
                              hipStream_t stream) {
  const float* gl_sa = (const float*)d_in[0];
  const float* lo_sa = (const float*)d_in[1];
  const float* gl_pr = (const float*)d_in[2];
  const float* coords = (const float*)d_in[3];
  float* ws = (float*)d_ws;
  float* out = (float*)d_out;

  zero_ws_kernel<<<(3 * NSLOTS + 255) / 256, 256, 0, stream>>>(ws);
  triplet_main<<<2048, 256, 0, stream>>>(gl_sa, lo_sa, gl_pr, coords, ws);
  finalize_kernel<<<1, 256, 0, stream>>>(ws, out);
}

// Round 3
// 210.514 us; speedup vs baseline: 2.5195x; 1.2026x over previous
//
#include <hip/hip_runtime.h>

#define NN 64
#define NSLOTS (14 * NN)             // 896 (term, n) slots
#define FRAG_U4 (128 * 8 * 14 * 64)  // gl_pr fragments, uint4 units (14.68 MB)
#define PART_OFF (FRAG_U4 * 4)       // float offset of per-block partials

typedef __attribute__((ext_vector_type(8))) short short8;
typedef __attribute__((ext_vector_type(4))) float f32x4;

__device__ __forceinline__ float waveSum(float v) {
#pragma unroll
  for (int m = 1; m < 64; m <<= 1) v += __shfl_xor(v, m, 64);
  return v;
}

// RNE float -> bf16
__device__ __forceinline__ unsigned short f2bf(float f) {
  unsigned u = __builtin_bit_cast(unsigned, f);
  u += 0x7FFFu + ((u >> 16) & 1u);
  return (unsigned short)(u >> 16);
}
__device__ __forceinline__ unsigned packbf(float a, float b) {
  return (unsigned)f2bf(a) | ((unsigned)f2bf(b) << 16);
}

// gl_pr (128 mats, 256ch x 196col fp32) -> bf16 fragments
// frag layout: [mat][kc8(8)][tile(14)][lane(64)][8 bf16]
// fragment(lane=quad*16+li, e) = element(ch = kc8*32+quad*8+e, col = tile*16+li)
__global__ void __launch_bounds__(256) convert_b_kernel(
    const float* __restrict__ gl_pr, uint4* __restrict__ frags) {
  const int b = blockIdx.x; // mat*8 + kc8
  const int mat = b >> 3, kc8 = b & 7;
  const int tid = threadIdx.x;
  const float* src = gl_pr + (size_t)mat * 256 * 196 + (size_t)kc8 * 32 * 196;
  uint4* dst = frags + (size_t)b * 14 * 64;
#pragma unroll
  for (int it = 0; it < 4; ++it) {
    int task = it * 256 + tid;
    if (task < 896) {
      int tile = task >> 6, l = task & 63;
      int li = l & 15, quad = l >> 4;
      int col = tile * 16 + li;
      const float* p = src + (size_t)(quad * 8) * 196 + col;
      float v[8];
#pragma unroll
      for (int e = 0; e < 8; ++e) v[e] = (col < 196) ? p[e * 196] : 0.0f;
      uint4 u;
      u.x = packbf(v[0], v[1]);
      u.y = packbf(v[2], v[3]);
      u.z = packbf(v[4], v[5]);
      u.w = packbf(v[6], v[7]);
      dst[task] = u;
    }
  }
}

__global__ void __launch_bounds__(256, 4) triplet_main(
    const float* __restrict__ gl_sa, const float* __restrict__ lo_sa,
    const uint4* __restrict__ bfrags, const float* __restrict__ coords,
    float* __restrict__ partials) {
  // lane-linear fragment LDS: wave accesses are contiguous 1 KB (conflict-free)
  __shared__ short bbuf[2][14][64][8]; // 28672 B
  __shared__ short abuf[2][4][64][8];  //  8192 B
  __shared__ float red[3][4];

  const int tid = threadIdx.x;
  const int lane = tid & 63;
  const int li = lane & 15;
  const int quad = lane >> 4;
  const int w = tid >> 6; // wave id = 16-row strip within 64-row group

  int b = blockIdx.x;
  const float *qptr, *cqp, *ckp;
  int Q, Wq, matk, rowbase;
  if (b < 512) {
    // gl terms: t=0 -> q=gl_sa[1],k=gl_pr[0]; t=1 -> q=gl_sa[0],k=gl_pr[1]
    int t = b >> 8, rem = b & 255;
    int n = rem >> 2, g = rem & 3;
    rowbase = g * 64;
    int qi = 1 - t, kj = t;
    Q = 196; Wq = 14;
    qptr = gl_sa + (size_t)(qi * NN + n) * 256 * 196;
    matk = kj * NN + n;
    cqp = coords + (qi * NN + n) * 4;
    ckp = coords + (kj * NN + n) * 4;
  } else {
    int bb = b - 512;
    int t = bb / 128, rem = bb % 128;
    int n = rem >> 1, g = rem & 1;
    rowbase = g * 64;
    int j = t / 6, i = t % 6;
    Q = 100; Wq = 10;
    qptr = lo_sa + (size_t)(i * NN + n) * 256 * 100;
    matk = j * NN + n;
    cqp = coords + ((2 + i) * NN + n) * 4;
    ckp = coords + (j * NN + n) * 4;
  }

  f32x4 acc[14];
#pragma unroll
  for (int t = 0; t < 14; ++t) acc[t] = 0.0f;

#pragma unroll 1
  for (int c0 = 0; c0 < 256; c0 += 64) {
    // ---- B: copy pre-converted fragments (2 kc x 14 tiles x 64 lanes) ----
    const uint4* bs = bfrags + (size_t)(matk * 8 + (c0 >> 5)) * 14 * 64;
#pragma unroll
    for (int it = 0; it < 7; ++it) {
      int idx = it * 4 + w; // 0..27, wave-uniform
      int kc = idx / 14, tile = idx % 14;
      uint4 u = bs[(kc * 14 + tile) * 64 + lane];
      *(uint4*)&bbuf[kc][tile][lane][0] = u;
    }
    // ---- A: fragment gather (2 kc x 4 row-tiles x 64 lanes = 512 tasks) ----
#pragma unroll
    for (int it = 0; it < 2; ++it) {
      int task = it * 256 + tid;
      int kc = task >> 8, rt = (task >> 6) & 3, l = task & 63;
      int ali = l & 15, aq = l >> 4;
      int row = rowbase + rt * 16 + ali;
      const float* p = qptr + (size_t)(c0 + kc * 32 + aq * 8) * Q + row;
      float v[8];
#pragma unroll
      for (int e = 0; e < 8; ++e) v[e] = (row < Q) ? p[e * Q] : 0.0f;
      uint4 u;
      u.x = packbf(v[0], v[1]);
      u.y = packbf(v[2], v[3]);
      u.z = packbf(v[4], v[5]);
      u.w = packbf(v[6], v[7]);
      *(uint4*)&abuf[kc][rt][l][0] = u;
    }
    __syncthreads();
    // ---- MFMA: 2 k-steps x 14 col-tiles ----
#pragma unroll
    for (int kc = 0; kc < 2; ++kc) {
      short8 af = *(const short8*)&abuf[kc][w][lane][0];
#pragma unroll
      for (int t = 0; t < 14; ++t) {
        short8 bf = *(const short8*)&bbuf[kc][t][lane][0];
        acc[t] = __builtin_amdgcn_mfma_f32_16x16x32_bf16(af, bf, acc[t], 0, 0, 0);
      }
    }
    __syncthreads();
  }

  // ---- geometry ----
  const float qx0 = cqp[0], qy0 = cqp[1];
  const float bwq = (cqp[2] - qx0) / (float)Wq;
  const float bhq = (cqp[3] - qy0) / (float)Wq;
  const float kx0 = ckp[0], ky0 = ckp[1];
  const float bwk = (ckp[2] - kx0) / 14.0f;
  const float bhk = (ckp[3] - ky0) / 14.0f;
  const float qd = sqrtf(bwq * bwq + bhq * bhq);
  const float kd = sqrtf(bwk * bwk + bhk * bhk);
  const float md = fmaxf(qd, kd);
  const float INFV = __builtin_inff();

  float ckx[14], cky[14];
  unsigned kvalid = 0;
#pragma unroll
  for (int t = 0; t < 14; ++t) {
    int col = t * 16 + li;
    if (col < 196) kvalid |= (1u << t);
    int xk = col % 14, yk = col / 14;
    ckx[t] = ((float)xk + 0.5f) * bwk + kx0;
    cky[t] = ((float)yk + 0.5f) * bhk + ky0;
  }

  // ---- fused epilogue on MFMA C layout: quad owns rows quad*4+reg ----
  float psum = 0.f, pcnt = 0.f, nsum = 0.f;
#pragma unroll
  for (int rg = 0; rg < 4; ++rg) {
    int r = rowbase + w * 16 + quad * 4 + rg; // quad-uniform
    if (r < Q) {
      int x = r % Wq, y = r / Wq;
      float cqx = ((float)x + 0.5f) * bwq + qx0;
      float cqy = ((float)y + 0.5f) * bhq + qy0;
      float mv[14];
#pragma unroll
      for (int t = 0; t < 14; ++t) {
        float v = -2.0f * acc[t][rg];
        float dx = cqx - ckx[t], dy = cqy - cky[t];
        float dist = sqrtf(dx * dx + dy * dy) / md;
        bool kv = (kvalid >> t) & 1;
        bool pos = kv && (dist < 0.7f);
        psum += pos ? v : 0.0f;
        pcnt += pos ? 1.0f : 0.0f;
        mv[t] = (kv && !pos) ? v : INFV;
      }
      float total = 0.f, first = 0.f;
#pragma unroll 1
      for (int s = 0; s < 10; ++s) {
        float lm = mv[0];
#pragma unroll
        for (int t = 1; t < 14; ++t) lm = fminf(lm, mv[t]);
        float m = lm;
        m = fminf(m, __shfl_xor(m, 1));
        m = fminf(m, __shfl_xor(m, 2));
        m = fminf(m, __shfl_xor(m, 4));
        m = fminf(m, __shfl_xor(m, 8));
        if (s == 0) first = m;
        total += m;
        unsigned long long bal = __ballot(lm == m);
        unsigned qb = (unsigned)((bal >> (quad * 16)) & 0xFFFFull);
        int leader = __ffs(qb) - 1;
        if (li == leader) {
          bool done = false;
#pragma unroll
          for (int t = 0; t < 14; ++t) {
            bool hit = !done && (mv[t] == m);
            mv[t] = hit ? INFV : mv[t];
            done = done || hit;
          }
        }
      }
      if (li == 0) nsum += (total - first) * (1.0f / 9.0f);
    }
  }

  psum = waveSum(psum);
  pcnt = waveSum(pcnt);
  nsum = waveSum(nsum);
  if (lane == 0) {
    red[0][w] = psum;
    red[1][w] = pcnt;
    red[2][w] = nsum;
  }
  __syncthreads();
  if (tid == 0) {
    float* pb = partials + (size_t)blockIdx.x * 3;
    pb[0] = red[0][0] + red[0][1] + red[0][2] + red[0][3];
    pb[1] = red[1][0] + red[1][1] + red[1][2] + red[1][3];
    pb[2] = red[2][0] + red[2][1] + red[2][2] + red[2][3];
  }
}

__global__ void __launch_bounds__(256) finalize_kernel(
    const float* __restrict__ partials, float* __restrict__ out) {
  int tid = threadIdx.x;
  float sum = 0.f;
  for (int e = tid; e < NSLOTS; e += 256) {
    float P = 0.f, C = 0.f, Ns = 0.f, Qf;
    if (e < 128) {
      int t = e >> 6, n = e & 63;
      Qf = 196.0f;
      int base = (t * 256 + n * 4) * 3;
#pragma unroll
      for (int g = 0; g < 4; ++g) {
        P += partials[base + 3 * g];
        C += partials[base + 3 * g + 1];
        Ns += partials[base + 3 * g + 2];
      }
    } else {
      int s = e - 128;
      int t = s >> 6, n = s & 63;
      Qf = 100.0f;
      int base = (512 + t * 128 + n * 2) * 3;
#pragma unroll
      for (int g = 0; g < 2; ++g) {
        P += partials[base + 3 * g];
        C += partials[base + 3 * g + 1];
        Ns += partials[base + 3 * g + 2];
      }
    }
    float positives = P / (C + 1e-6f);
    float negatives = Ns / Qf;
    sum += fmaxf(0.0f, 100.0f - (negatives - 2.0f * positives));
  }
  sum = waveSum(sum);
  __shared__ float ssum[4];
  if ((tid & 63) == 0) ssum[tid >> 6] = sum;
  __syncthreads();
  if (tid == 0) out[0] = (ssum[0] + ssum[1] + ssum[2] + ssum[3]) * (1.0f / NSLOTS);
}

extern "C" void kernel_launch(void* const* d_in, const int* in_sizes, int n_in,
                              void* d_out, int out_size, void* d_ws, size_t ws_size,
                              hipStream_t stream) {
  const float* gl_sa = (const float*)d_in[0];
  const float* lo_sa = (const float*)d_in[1];
  const float* gl_pr = (const float*)d_in[2];
  const float* coords = (const float*)d_in[3];
  uint4* frags = (uint4*)d_ws;
  float* partials = (float*)d_ws + PART_OFF;
  float* out = (float*)d_out;

  convert_b_kernel<<<1024, 256, 0, stream>>>(gl_pr, frags);
  triplet_main<<<2048, 256, 0, stream>>>(gl_sa, lo_sa, frags, coords, partials);
  finalize_kernel<<<1, 256, 0, stream>>>(partials, out);
}